// Round 12
// baseline (1556.664 us; speedup 1.0000x reference)
//
#include <hip/hip_runtime.h>
#include <hip/hip_bf16.h>
#include <stdint.h>

// Problem constants
#define BATCH 256
#define SEQT  200
#define IND   128
#define HID   256
#define G3    768   // 3*HID
#define OUTD  118

#define TC    25    // steps per pipeline chunk
#define NC    8     // chunks (TC*NC == SEQT)
#define G0TILES 300 // gemm tiles per chunk (per layer): (51200/8 rows /128) * 6

#define HSTRIDE 264  // h-state LDS row stride in shorts
#define W0SZ (G3*IND)
#define WHSZ (G3*HID)
#define XSZ  (BATCH*SEQT*IND)

#define SLOT_F  (BATCH*TC*G3)      // floats per gx ring slot (4,915,200)
#define SLOTP_F (SLOT_F + 2048)    // +8KB pad: 2-deep prefetch runs 2 rows past end

// flag indices (int flg[32], zeroed by cvt_all each run)
#define FH1 0      // [0..7]   scan0 blocks done per chunk (target 64)
#define FS1 8      // [8..15]  scan1 blocks done per chunk (target 64)
#define FG0 16     // [16..23] gemm0 tiles done per chunk (target 300)
#define FG1 24     // [24..31] gemm1 tiles done per chunk (target 300)

#define NLOG2E (-1.44269504f)
#define LOG2E2 2.88539008f

typedef short  short8 __attribute__((ext_vector_type(8)));
typedef float  f32x4  __attribute__((ext_vector_type(4)));
typedef int    i32x4  __attribute__((ext_vector_type(4)));

__device__ __forceinline__ float exp2fast(float x) {
#if __has_builtin(__builtin_amdgcn_exp2f)
    return __builtin_amdgcn_exp2f(x);
#else
    return exp2f(x);
#endif
}

__device__ __forceinline__ unsigned short f2bf(float x) {
    union { float f; uint32_t u; } v; v.f = x;
    uint32_t u = v.u;
    u += 0x7FFF + ((u >> 16) & 1);   // round-to-nearest-even
    return (unsigned short)(u >> 16);
}

// Scan-loop barrier: drain LDS ops only; global loads/stores stay in flight.
__device__ __forceinline__ void scan_barrier() {
    asm volatile("s_waitcnt lgkmcnt(0)" ::: "memory");
    __builtin_amdgcn_s_barrier();
    __builtin_amdgcn_sched_barrier(0);
}

// Device-scope acquire spin (thread 0 only; block released via __syncthreads).
__device__ __forceinline__ void spin_ge(int* p, int tgt) {
    while (__hip_atomic_load(p, __ATOMIC_ACQUIRE, __HIP_MEMORY_SCOPE_AGENT) < tgt)
        __builtin_amdgcn_s_sleep(2);
}

// Coherent (agent-scope) dword load: bypasses the consumer XCD's potentially
// STALE L1/L2 for ring-buffer data rewritten within one kernel (G16 hazard --
// the producer's release flushes ITS caches, it can't invalidate OURS).
__device__ __forceinline__ float gloadf(const float* p) {
    return __hip_atomic_load(p, __ATOMIC_RELAXED, __HIP_MEMORY_SCOPE_AGENT);
}
__device__ __forceinline__ uint32_t gloadu(const uint32_t* p) {
    return __hip_atomic_load(p, __ATOMIC_RELAXED, __HIP_MEMORY_SCOPE_AGENT);
}

// Fused float4-vectorized conversion: x + all four weight matrices.
// Also zeroes the 32 pipeline flags (runs before persist on the stream).
__global__ void cvt_all(const float* __restrict__ x,
                        const float* __restrict__ w0,  const float* __restrict__ wh0,
                        const float* __restrict__ w1,  const float* __restrict__ wh1,
                        unsigned short* __restrict__ xb,
                        unsigned short* __restrict__ o0,  unsigned short* __restrict__ oh0,
                        unsigned short* __restrict__ o1,  unsigned short* __restrict__ oh1,
                        int* __restrict__ flg) {
    const int n4 = (XSZ + W0SZ + 3 * WHSZ) / 4;
    int idx = blockIdx.x * blockDim.x + threadIdx.x;
    if (idx < 32) flg[idx] = 0;
    int stride = gridDim.x * blockDim.x;
    for (int i = idx; i < n4; i += stride) {
        int j = i * 4;
        const float* src; unsigned short* dst;
        if (j < XSZ) { src = x; dst = xb; }
        else {
            j -= XSZ;
            if (j < W0SZ) { src = w0; dst = o0; }
            else {
                j -= W0SZ;
                if (j < WHSZ) { src = wh0; dst = oh0; }
                else {
                    j -= WHSZ;
                    if (j < WHSZ) { src = w1; dst = o1; }
                    else { j -= WHSZ; src = wh1; dst = oh1; }
                }
            }
        }
        float4 v = *(const float4*)(src + j);
        ushort4 o;
        o.x = f2bf(v.x); o.y = f2bf(v.y); o.z = f2bf(v.z); o.w = f2bf(v.w);
        *(ushort4*)(dst + j) = o;
    }
}

__global__ void combine_bias(const float* __restrict__ bih0, const float* __restrict__ bhh0,
                             const float* __restrict__ bih1, const float* __restrict__ bhh1,
                             float* __restrict__ bc0, float* __restrict__ bc1) {
    int i = blockIdx.x * blockDim.x + threadIdx.x;
    if (i < G3) bc0[i] = bih0[i] + (i < 2 * HID ? bhh0[i] : 0.0f);
    else if (i < 2 * G3) {
        int j = i - G3;
        bc1[j] = bih1[j] + (j < 2 * HID ? bhh1[j] : 0.0f);
    }
}

// ---- gemm unit (256 threads), chunk-rows [b][lt] layout in C slot ----
// COH: A panel written by another block THIS kernel (h1b) -> coherent loads.
template<int K, bool COH>
__device__ __forceinline__ void g_stage(i32x4* sA, int tile, int t0,
    const unsigned short* A, const unsigned short* Bt, const float* bias,
    int tidu, short8 (&b)[2][8], float& bia0, float& bia1, int& g0o)
{
    constexpr int KS = K / 32, CPR = K / 8, LSTR = CPR + 1, PT = 128 * CPR / 256;
    const int wave = tidu >> 6, lane = tidu & 63, col = lane & 15, quad = lane >> 4;
    const int nb = tile % 6, panel = tile / 6;
    const int g0 = nb * 128 + wave * 32 + col;
    g0o = g0;
#pragma unroll
    for (int jt = 0; jt < 2; jt++)
#pragma unroll
        for (int ks = 0; ks < KS; ks++)
            b[jt][ks] = *(const short8*)(Bt + (size_t)(g0 + jt * 16) * K + ks * 32 + quad * 8);
    bia0 = bias[g0]; bia1 = bias[g0 + 16];

    i32x4 st[PT];
#pragma unroll
    for (int i = 0; i < PT; i++) {
        int g = i * 256 + tidu;
        int row = g / CPR, cc = g % CPR;
        int r = panel * 128 + row;
        int bb = r / TC, lt = r - bb * TC;
        const unsigned short* src = A + (size_t)(bb * SEQT + t0 + lt) * K + cc * 8;
        if constexpr (COH) {
            const uint32_t* q = (const uint32_t*)src;
            i32x4 v;
            v[0] = (int)gloadu(q + 0);
            v[1] = (int)gloadu(q + 1);
            v[2] = (int)gloadu(q + 2);
            v[3] = (int)gloadu(q + 3);
            st[i] = v;
        } else {
            st[i] = *(const i32x4*)src;
        }
    }
#pragma unroll
    for (int i = 0; i < PT; i++) {
        int g = i * 256 + tidu;
        sA[(g / CPR) * LSTR + (g % CPR)] = st[i];
    }
}

template<int K>
__device__ __forceinline__ void g_comp(const i32x4* sA, int tile,
    const short8 (&b)[2][8], float bia0, float bia1, int g0,
    float* Cslot, int tidu)
{
    constexpr int KS = K / 32, CPR = K / 8, LSTR = CPR + 1;
    const int lane = tidu & 63, col = lane & 15, quad = lane >> 4;
    const int nb = tile % 6, panel = tile / 6;
    const float scl = (nb < 4) ? NLOG2E : LOG2E2;
#pragma unroll 2
    for (int ms = 0; ms < 8; ms++) {
        f32x4 a0 = (f32x4)(0.0f), a1 = (f32x4)(0.0f);
#pragma unroll
        for (int ks = 0; ks < KS; ks++) {
            short8 a = __builtin_bit_cast(short8, sA[(ms * 16 + col) * LSTR + ks * 4 + quad]);
            a0 = __builtin_amdgcn_mfma_f32_16x16x32_bf16(a, b[0][ks], a0, 0, 0, 0);
            a1 = __builtin_amdgcn_mfma_f32_16x16x32_bf16(a, b[1][ks], a1, 0, 0, 0);
        }
        float* crow = Cslot + (size_t)(panel * 128 + ms * 16 + quad * 4) * G3 + g0;
#pragma unroll
        for (int r = 0; r < 4; r++) {
            crow[(size_t)r * G3]      = (a0[r] + bia0) * scl;
            crow[(size_t)r * G3 + 16] = (a1[r] + bia1) * scl;
        }
    }
}

// ---- persistent producer-consumer pipeline kernel ----
// REGULAR launch (no cooperative API -- graph-capture-safe): co-residency is
// physically forced by 152KB static LDS (1 block/CU) with grid = 256 = #CUs,
// so all blocks are dispatched and resident immediately.
//   blocks [0,64):    scan0 (4 batches/WG) -- weights loaded ONCE, h in regs
//   blocks [64,128):  scan1
//   blocks [128,256): gemm (2 units x 256 thr; 1-2 tiles/unit/chunk/layer)
// Sync: device-scope counting flags (release = threadfence+sync+atomicAdd;
// acquire = thread0 atomic-load spin + syncthreads). Consumers read
// ring-buffer payloads via agent-scope loads (stale-L2 hazard, see gloadf).
// Ring backpressure: gemm0(c) waits f_h1[c-2]; gemm1(c) waits f_h1[c] and
// f_s1[c-2]. Acyclic pipeline DAG -> deadlock-free.
__global__ __launch_bounds__(512, 2) void persist(
    const unsigned short* xb,
    unsigned short* h1b,
    const unsigned short* w0b, const unsigned short* w1b,
    const float* bc0, const float* bc1,
    float* gx0, float* gx1,                   // 2-slot rings, [b][TC][G3] per slot
    const unsigned short* wh0, const unsigned short* wh1,
    const float* bhh0, const float* bhh1,
    float* hlast, int* flg)
{
    __shared__ __attribute__((aligned(16))) char SM[16896 + 135168];

    const int bid = blockIdx.x;
    const int tid = threadIdx.x;

    if (bid < 128) {
        // ================= scan role (4 batches/WG, persistent) =================
        const bool L0 = bid < 64;
        const unsigned short* Whh = L0 ? wh0 : wh1;
        const float* bhh = L0 ? bhh0 : bhh1;
        float* gxb = L0 ? gx0 : gx1;
        unsigned short* h1o = L0 ? h1b : nullptr;
        const int wg = L0 ? bid : bid - 64;
        int* fgx   = flg + (L0 ? FG0 : FG1);
        int* fdone = flg + (L0 ? FH1 : FS1);

        unsigned short* hs = (unsigned short*)SM;   // [2][16*HSTRIDE]

        const int wave = tid >> 6, lane = tid & 63;
        const int col = lane & 15, quad = lane >> 4;
        const int jbase = wave * 32, j0 = jbase + col, j1 = jbase + 16 + col;
        const int bq  = wg * 4 + quad;        // this lane's batch
        const int row = quad * 4;             // its live MFMA row

        // r,z weights (both jt) -> 128 pinned VGPRs (loaded ONCE for all 200 steps)
        i32x4 wrz[2][2][8];
#pragma unroll
        for (int g = 0; g < 2; g++)
#pragma unroll
            for (int jt = 0; jt < 2; jt++)
#pragma unroll
                for (int ks = 0; ks < 8; ks++)
                    wrz[g][jt][ks] = *(const i32x4*)(
                        Whh + (size_t)(g * HID + jbase + jt * 16 + col) * HID + ks * 32 + quad * 8);
        // n-gate jt0 / jt1 -> 64 pinned VGPRs
        i32x4 wn0[8], wn1r[8];
#pragma unroll
        for (int ks = 0; ks < 8; ks++) {
            wn0[ks]  = *(const i32x4*)(Whh + (size_t)(2 * HID + j0) * HID + ks * 32 + quad * 8);
            wn1r[ks] = *(const i32x4*)(Whh + (size_t)(2 * HID + j1) * HID + ks * 32 + quad * 8);
        }

        // zero both h buffers once (rows != 0 mod 4 stay zero: MFMA padding;
        // live rows start 0 == h0)
        for (int i = tid; i < 2 * 16 * HSTRIDE; i += 512) hs[i] = 0;

        float hreg[2] = { 0.0f, 0.0f };       // fp32 h, registers for all 200 steps
        float bhn[2] = { bhh[2 * HID + j0], bhh[2 * HID + j1] };
        const int abase = col * HSTRIDE + quad * 8;
        const int wbase = row * HSTRIDE + j0;

        __syncthreads();

        int cur = 0;                          // h double-buffer toggle, runs across chunks
        for (int c = 0; c < NC; ++c) {
            if (tid == 0) spin_ge(&fgx[c], G0TILES);   // acquire: chunk's gx ready
            __syncthreads();

            const float* gxslot = gxb + (size_t)(c & 1) * SLOTP_F;
            int gof = (bq * TC) * G3 + j0;
            int hof = (bq * SEQT + c * TC) * HID + j0;

            // 2-deep gx prefetch (gc = lt, gc1 = lt+1, gc2 = lt+2 in flight)
            float gc[3][2], gc1[3][2], gc2[3][2];
#pragma unroll
            for (int g3 = 0; g3 < 3; g3++) {
                gc[g3][0] = gloadf(gxslot + gof + g3 * HID);
                gc[g3][1] = gloadf(gxslot + gof + g3 * HID + 16);
            }
            gof += G3;
#pragma unroll
            for (int g3 = 0; g3 < 3; g3++) {
                gc1[g3][0] = gloadf(gxslot + gof + g3 * HID);
                gc1[g3][1] = gloadf(gxslot + gof + g3 * HID + 16);
            }
            gof += G3;

            for (int lt = 0; lt < TC; lt++) {
                unsigned short* hc = hs + cur * 16 * HSTRIDE;
                unsigned short* hn = hs + (cur ^ 1) * 16 * HSTRIDE;

                // pin weight regs: opaque per-iter redefinition blocks remat
#pragma unroll
                for (int g = 0; g < 2; g++)
#pragma unroll
                    for (int jt = 0; jt < 2; jt++)
#pragma unroll
                        for (int ks = 0; ks < 8; ks++)
                            asm volatile("" : "+v"(wrz[g][jt][ks]));
#pragma unroll
                for (int ks = 0; ks < 8; ks++) {
                    asm volatile("" : "+v"(wn0[ks]));
                    asm volatile("" : "+v"(wn1r[ks]));
                }

                // issue prefetch for lt+2 (slot tail-padded; tail discarded)
#pragma unroll
                for (int g3 = 0; g3 < 3; g3++) {
                    gc2[g3][0] = gloadf(gxslot + gof + g3 * HID);
                    gc2[g3][1] = gloadf(gxslot + gof + g3 * HID + 16);
                }
                gof += G3;

                f32x4 acc[3][2];
#pragma unroll
                for (int g = 0; g < 3; g++)
#pragma unroll
                    for (int jt = 0; jt < 2; jt++) acc[g][jt] = (f32x4)(0.0f);

                __builtin_amdgcn_s_setprio(1);
#pragma unroll
                for (int ks = 0; ks < 8; ks++) {
                    short8 a = *(const short8*)(&hc[abase + ks * 32]);
                    acc[0][0] = __builtin_amdgcn_mfma_f32_16x16x32_bf16(a, __builtin_bit_cast(short8, wrz[0][0][ks]), acc[0][0], 0, 0, 0);
                    acc[0][1] = __builtin_amdgcn_mfma_f32_16x16x32_bf16(a, __builtin_bit_cast(short8, wrz[0][1][ks]), acc[0][1], 0, 0, 0);
                    acc[1][0] = __builtin_amdgcn_mfma_f32_16x16x32_bf16(a, __builtin_bit_cast(short8, wrz[1][0][ks]), acc[1][0], 0, 0, 0);
                    acc[1][1] = __builtin_amdgcn_mfma_f32_16x16x32_bf16(a, __builtin_bit_cast(short8, wrz[1][1][ks]), acc[1][1], 0, 0, 0);
                    acc[2][0] = __builtin_amdgcn_mfma_f32_16x16x32_bf16(a, __builtin_bit_cast(short8, wn0[ks]),       acc[2][0], 0, 0, 0);
                    acc[2][1] = __builtin_amdgcn_mfma_f32_16x16x32_bf16(a, __builtin_bit_cast(short8, wn1r[ks]),      acc[2][1], 0, 0, 0);
                }
                __builtin_amdgcn_s_setprio(0);

                unsigned short hb[2];
#pragma unroll
                for (int jt = 0; jt < 2; jt++) {
                    float er = exp2fast(__builtin_fmaf(acc[0][jt][0], NLOG2E, gc[0][jt]));
                    float rr = __builtin_amdgcn_rcpf(1.0f + er);
                    float ez = exp2fast(__builtin_fmaf(acc[1][jt][0], NLOG2E, gc[1][jt]));
                    float zz = __builtin_amdgcn_rcpf(1.0f + ez);
                    float inner = acc[2][jt][0] + bhn[jt];
                    float en = exp2fast(__builtin_fmaf(rr * inner, LOG2E2, gc[2][jt]));
                    float nn = __builtin_fmaf(__builtin_amdgcn_rcpf(1.0f + en), -2.0f, 1.0f);
                    float hnew = __builtin_fmaf(zz, hreg[jt] - nn, nn);
                    hreg[jt] = hnew;
                    hb[jt] = f2bf(hnew);
                    hn[wbase + jt * 16] = hb[jt];
                }

                if (h1o) {
                    h1o[hof]      = hb[0];
                    h1o[hof + 16] = hb[1];
                }
                hof += HID;

                // rotate prefetch buffers (static-indexed register moves)
#pragma unroll
                for (int g3 = 0; g3 < 3; g3++) {
                    gc[g3][0]  = gc1[g3][0];  gc[g3][1]  = gc1[g3][1];
                    gc1[g3][0] = gc2[g3][0];  gc1[g3][1] = gc2[g3][1];
                }

                cur ^= 1;
                scan_barrier();
            }

            // release: h1 chunk written (scan0) / gx slot consumed (both)
            __threadfence();
            __syncthreads();
            if (tid == 0)
                __hip_atomic_fetch_add(&fdone[c], 1, __ATOMIC_RELEASE, __HIP_MEMORY_SCOPE_AGENT);
        }

        if (!L0) {   // scan1: final h -> fc input
            hlast[bq * HID + j0]      = hreg[0];
            hlast[bq * HID + j0 + 16] = hreg[1];
        }

    } else {
        // ================= gemm role (persistent producer) =================
        const int g  = bid - 128;                 // 0..127
        const int uu = g * 2 + (tid >> 8);        // unit id 0..255
        const int tidu = tid & 255;
        const int ub = uu * G0TILES / 256;        // this unit's tile range
        const int ue = (uu + 1) * G0TILES / 256;  // (1-2 tiles)
        i32x4* sA = (i32x4*)(SM + 16896) + (tid >> 8) * 4224;

        // tiles produced by this BLOCK per chunk (both units, telescoping sum = 300)
        const int blkTiles = ((g * 2 + 2) * G0TILES / 256) - ((g * 2) * G0TILES / 256);

        short8 bf[2][8];
        float bia0, bia1; int g0c;

        for (int cc = 0; cc < NC + 2; ++cc) {
            const int c0 = cc, c1 = cc - 2;
            const bool do0 = (c0 < NC), do1 = (c1 >= 0);

            if (tid == 0) {
                if (do0 && c0 >= 2) spin_ge(&flg[FH1 + c0 - 2], 64);   // gx0 slot free
                if (do1) {
                    spin_ge(&flg[FH1 + c1], 64);                       // h1 chunk ready
                    if (c1 >= 2) spin_ge(&flg[FS1 + c1 - 2], 64);      // gx1 slot free
                }
            }
            __syncthreads();

            float* s0 = gx0 + (size_t)(c0 & 1) * SLOTP_F;
            float* s1 = gx1 + (size_t)(c1 & 1) * SLOTP_F;

#pragma unroll 1
            for (int r = 0; r < 2; ++r) {       // gemm0 rounds (uniform barriers)
                int t = ub + r; bool act = do0 && (t < ue);
                if (act) g_stage<IND, false>(sA, t, c0 * TC, xb, w0b, bc0, tidu, bf, bia0, bia1, g0c);
                __syncthreads();
                if (act) g_comp<IND>(sA, t, bf, bia0, bia1, g0c, s0, tidu);
                __syncthreads();
            }
#pragma unroll 1
            for (int r = 0; r < 2; ++r) {       // gemm1 rounds (h1b = coherent reads)
                int t = ub + r; bool act = do1 && (t < ue);
                if (act) g_stage<HID, true>(sA, t, c1 * TC, h1b, w1b, bc1, tidu, bf, bia0, bia1, g0c);
                __syncthreads();
                if (act) g_comp<HID>(sA, t, bf, bia0, bia1, g0c, s1, tidu);
                __syncthreads();
            }

            // release both layers' tiles
            __threadfence();
            __syncthreads();
            if (tid == 0) {
                if (do0) __hip_atomic_fetch_add(&flg[FG0 + c0], blkTiles, __ATOMIC_RELEASE, __HIP_MEMORY_SCOPE_AGENT);
                if (do1) __hip_atomic_fetch_add(&flg[FG1 + c1], blkTiles, __ATOMIC_RELEASE, __HIP_MEMORY_SCOPE_AGENT);
            }
        }
    }
}

// out[256,118] = hlast[256,256] @ fcW[118,256]^T + fcb
__global__ __launch_bounds__(128) void fc_kernel(
    const float* __restrict__ hlast, const float* __restrict__ W,
    const float* __restrict__ b, float* __restrict__ out)
{
    __shared__ float hsm[HID];
    int bidx = blockIdx.x;
    for (int i = threadIdx.x; i < HID; i += 128) hsm[i] = hlast[(size_t)bidx * HID + i];
    __syncthreads();
    int o = threadIdx.x;
    if (o < OUTD) {
        float acc = b[o];
        const float* wrow = W + (size_t)o * HID;
#pragma unroll 4
        for (int k = 0; k < HID; k++) acc += hsm[k] * wrow[k];
        out[(size_t)bidx * OUTD + o] = acc;
    }
}

extern "C" void kernel_launch(void* const* d_in, const int* in_sizes, int n_in,
                              void* d_out, int out_size, void* d_ws, size_t ws_size,
                              hipStream_t stream) {
    const float* x    = (const float*)d_in[0];
    const float* Wih0 = (const float*)d_in[1];
    const float* Whh0 = (const float*)d_in[2];
    const float* bih0 = (const float*)d_in[3];
    const float* bhh0 = (const float*)d_in[4];
    const float* Wih1 = (const float*)d_in[5];
    const float* Whh1 = (const float*)d_in[6];
    const float* bih1 = (const float*)d_in[7];
    const float* bhh1 = (const float*)d_in[8];
    const float* fcW  = (const float*)d_in[9];
    const float* fcb  = (const float*)d_in[10];
    float* out = (float*)d_out;

    char* ws = (char*)d_ws;
    size_t off = 0;
    auto walloc = [&](size_t bytes) {
        void* p = ws + off;
        off = (off + bytes + 255) & ~(size_t)255;
        return p;
    };

    const int M = BATCH * SEQT;                       // 51200
    unsigned short* xb   = (unsigned short*)walloc((size_t)XSZ * 2);         // 13.1 MB
    float*          gx0  = (float*)         walloc((size_t)2 * SLOTP_F * 4); // 39.3 MB
    float*          gx1  = (float*)         walloc((size_t)2 * SLOTP_F * 4); // 39.3 MB
    unsigned short* h1b  = (unsigned short*)walloc((size_t)M * HID * 2);     // 26.2 MB
    unsigned short* w0b  = (unsigned short*)walloc((size_t)W0SZ * 2);
    unsigned short* wh0b = (unsigned short*)walloc((size_t)WHSZ * 2);
    unsigned short* w1b  = (unsigned short*)walloc((size_t)WHSZ * 2);
    unsigned short* wh1b = (unsigned short*)walloc((size_t)WHSZ * 2);
    float*          bc0  = (float*)         walloc(G3 * 4);
    float*          bc1  = (float*)         walloc(G3 * 4);
    float*          hlast= (float*)         walloc((size_t)BATCH * HID * 4);
    int*            flg  = (int*)           walloc(32 * 4);

    cvt_all     <<<2048, 256, 0, stream>>>(x, Wih0, Whh0, Wih1, Whh1,
                                           xb, w0b, wh0b, w1b, wh1b, flg);
    combine_bias<<<6,    256, 0, stream>>>(bih0, bhh0, bih1, bhh1, bc0, bc1);

    // persistent pipeline: REGULAR launch (graph-capture-safe). Co-residency
    // forced by 152KB LDS (1 block/CU) with grid = 256 = #CUs.
    persist<<<256, 512, 0, stream>>>(xb, h1b, w0b, w1b, bc0, bc1,
                                     gx0, gx1, wh0b, wh1b, bhh0, bhh1,
                                     hlast, flg);

    fc_kernel<<<BATCH, 128, 0, stream>>>(hlast, fcW, fcb, out);
}

// Round 13
// 453.400 us; speedup vs baseline: 3.4333x; 3.4333x over previous
//
#include <hip/hip_runtime.h>
#include <hip/hip_bf16.h>
#include <stdint.h>

// Problem constants
#define BATCH 256
#define SEQT  200
#define IND   128
#define HID   256
#define G3    768   // 3*HID
#define OUTD  118

#define TC    25    // steps per pipeline chunk
#define NC    8     // chunks (TC*NC == SEQT)
#define G0TILES 300 // gemm tiles per chunk (per layer): (51200/8 rows /128) * 6

#define HSTRIDE 264  // h-state LDS row stride in shorts
#define W0SZ (G3*IND)
#define WHSZ (G3*HID)
#define XSZ  (BATCH*SEQT*IND)

#define SLOT_F  (BATCH*TC*G3)      // floats per gx ring slot (4,915,200)
#define SLOTP_F (SLOT_F + 2048)    // +8KB pad: 2-deep prefetch runs 2 rows past end

// packed-weight sizes (i32x4 entries)
#define SCANPK_L (48*512)          // per layer: 48 entries x 512 tid
#define G0PK     (8*1536)          // layer0 gemm B: 8 entries x (6 nb x 256 tidu)
#define G1PK     (16*1536)         // layer1 gemm B: 16 entries x 1536
#define PKTOT    (2*SCANPK_L + G0PK + G1PK)   // 86016

#define NLOG2E (-1.44269504f)
#define LOG2E2 2.88539008f

typedef short  short8 __attribute__((ext_vector_type(8)));
typedef float  f32x4  __attribute__((ext_vector_type(4)));
typedef int    i32x4  __attribute__((ext_vector_type(4)));

__device__ __forceinline__ float exp2fast(float x) {
#if __has_builtin(__builtin_amdgcn_exp2f)
    return __builtin_amdgcn_exp2f(x);
#else
    return exp2f(x);
#endif
}

__device__ __forceinline__ unsigned short f2bf(float x) {
    union { float f; uint32_t u; } v; v.f = x;
    uint32_t u = v.u;
    u += 0x7FFF + ((u >> 16) & 1);   // round-to-nearest-even
    return (unsigned short)(u >> 16);
}

// Scan-loop barrier: drain LDS ops only; global loads/stores stay in flight.
__device__ __forceinline__ void scan_barrier() {
    asm volatile("s_waitcnt lgkmcnt(0)" ::: "memory");
    __builtin_amdgcn_s_barrier();
    __builtin_amdgcn_sched_barrier(0);
}

// Fused float4-vectorized conversion: x + all four weight matrices.
__global__ void cvt_all(const float* __restrict__ x,
                        const float* __restrict__ w0,  const float* __restrict__ wh0,
                        const float* __restrict__ w1,  const float* __restrict__ wh1,
                        unsigned short* __restrict__ xb,
                        unsigned short* __restrict__ o0,  unsigned short* __restrict__ oh0,
                        unsigned short* __restrict__ o1,  unsigned short* __restrict__ oh1) {
    const int n4 = (XSZ + W0SZ + 3 * WHSZ) / 4;
    int idx = blockIdx.x * blockDim.x + threadIdx.x;
    int stride = gridDim.x * blockDim.x;
    for (int i = idx; i < n4; i += stride) {
        int j = i * 4;
        const float* src; unsigned short* dst;
        if (j < XSZ) { src = x; dst = xb; }
        else {
            j -= XSZ;
            if (j < W0SZ) { src = w0; dst = o0; }
            else {
                j -= W0SZ;
                if (j < WHSZ) { src = wh0; dst = oh0; }
                else {
                    j -= WHSZ;
                    if (j < WHSZ) { src = w1; dst = o1; }
                    else { j -= WHSZ; src = wh1; dst = oh1; }
                }
            }
        }
        float4 v = *(const float4*)(src + j);
        ushort4 o;
        o.x = f2bf(v.x); o.y = f2bf(v.y); o.z = f2bf(v.z); o.w = f2bf(v.w);
        *(ushort4*)(dst + j) = o;
    }
}

// Pre-pack weights into per-lane fragment order, LANE-MAJOR ([entry][tid]):
// the per-launch scan prologue (48 x dwordx4/thread, was 512B-stride gathers
// re-paid 11x = ~50MB/launch) becomes fully-coalesced wave-contiguous loads.
// Same for the gemm B fragments ([entry][nb*256+tidu]).
__global__ void pack_weights(const unsigned short* __restrict__ wh0b,
                             const unsigned short* __restrict__ wh1b,
                             const unsigned short* __restrict__ w0b,
                             const unsigned short* __restrict__ w1b,
                             i32x4* __restrict__ whp0, i32x4* __restrict__ whp1,
                             i32x4* __restrict__ gbp0, i32x4* __restrict__ gbp1) {
    int idx = blockIdx.x * blockDim.x + threadIdx.x;
    if (idx < 2 * SCANPK_L) {
        int l = idx / SCANPK_L, r = idx % SCANPK_L;
        int e = r / 512, tid = r % 512;           // [e][tid]
        int wave = tid >> 6, lane = tid & 63, col = lane & 15, quad = lane >> 4;
        int jbase = wave * 32;
        int row, ks;
        if (e < 32)      { int g = e >> 4, jt = (e >> 3) & 1; ks = e & 7;
                           row = g * HID + jbase + jt * 16 + col; }
        else if (e < 40) { ks = e - 32; row = 2 * HID + jbase + col; }
        else             { ks = e - 40; row = 2 * HID + jbase + 16 + col; }
        const unsigned short* W = l ? wh1b : wh0b;
        (l ? whp1 : whp0)[r] = *(const i32x4*)(W + (size_t)row * HID + ks * 32 + quad * 8);
    } else if (idx < 2 * SCANPK_L + G0PK) {
        int r = idx - 2 * SCANPK_L;
        int e = r / 1536, rem = r % 1536;          // [e][nb*256+tidu], KS=4
        int nb = rem / 256, tidu = rem % 256;
        int jt = e >> 2, ks = e & 3;
        int wave = tidu >> 6, lane = tidu & 63, col = lane & 15, quad = lane >> 4;
        int g0 = nb * 128 + wave * 32 + col;
        gbp0[r] = *(const i32x4*)(w0b + (size_t)(g0 + jt * 16) * IND + ks * 32 + quad * 8);
    } else if (idx < PKTOT) {
        int r = idx - 2 * SCANPK_L - G0PK;
        int e = r / 1536, rem = r % 1536;          // KS=8
        int nb = rem / 256, tidu = rem % 256;
        int jt = e >> 3, ks = e & 7;
        int wave = tidu >> 6, lane = tidu & 63, col = lane & 15, quad = lane >> 4;
        int g0 = nb * 128 + wave * 32 + col;
        gbp1[r] = *(const i32x4*)(w1b + (size_t)(g0 + jt * 16) * HID + ks * 32 + quad * 8);
    }
}

__global__ void combine_bias(const float* __restrict__ bih0, const float* __restrict__ bhh0,
                             const float* __restrict__ bih1, const float* __restrict__ bhh1,
                             float* __restrict__ bc0, float* __restrict__ bc1) {
    int i = blockIdx.x * blockDim.x + threadIdx.x;
    if (i < G3) bc0[i] = bih0[i] + (i < 2 * HID ? bhh0[i] : 0.0f);
    else if (i < 2 * G3) {
        int j = i - G3;
        bc1[j] = bih1[j] + (j < 2 * HID ? bhh1[j] : 0.0f);
    }
}

// ---- gemm unit (256 threads), chunk-rows [b][lt] layout in C slot ----
template<int K>
__device__ __forceinline__ void g_stage(i32x4* sA, int tile, int t0,
    const unsigned short* A, const i32x4* gbp, const float* bias,
    int tidu, short8 (&b)[2][8], float& bia0, float& bia1, int& g0o)
{
    constexpr int KS = K / 32, CPR = K / 8, LSTR = CPR + 1, PT = 128 * CPR / 256;
    const int wave = tidu >> 6, lane = tidu & 63, col = lane & 15, quad = lane >> 4;
    const int nb = tile % 6, panel = tile / 6;
    const int g0 = nb * 128 + wave * 32 + col;
    g0o = g0;
    // packed B: [e][nb*256+tidu], e = jt*KS+ks -> coalesced dwordx4 loads
    const i32x4* bp = gbp + nb * 256 + tidu;
#pragma unroll
    for (int jt = 0; jt < 2; jt++)
#pragma unroll
        for (int ks = 0; ks < KS; ks++)
            b[jt][ks] = __builtin_bit_cast(short8, bp[(jt * KS + ks) * 1536]);
    bia0 = bias[g0]; bia1 = bias[g0 + 16];

    i32x4 st[PT];
#pragma unroll
    for (int i = 0; i < PT; i++) {
        int g = i * 256 + tidu;
        int row = g / CPR, cc = g % CPR;
        int r = panel * 128 + row;
        int bb = r / TC, lt = r - bb * TC;
        st[i] = *(const i32x4*)(A + (size_t)(bb * SEQT + t0 + lt) * K + cc * 8);
    }
#pragma unroll
    for (int i = 0; i < PT; i++) {
        int g = i * 256 + tidu;
        sA[(g / CPR) * LSTR + (g % CPR)] = st[i];
    }
}

template<int K>
__device__ __forceinline__ void g_comp(const i32x4* sA, int tile,
    const short8 (&b)[2][8], float bia0, float bia1, int g0,
    float* Cslot, int tidu)
{
    constexpr int KS = K / 32, CPR = K / 8, LSTR = CPR + 1;
    const int lane = tidu & 63, col = lane & 15, quad = lane >> 4;
    const int nb = tile % 6, panel = tile / 6;
    const float scl = (nb < 4) ? NLOG2E : LOG2E2;
#pragma unroll 2
    for (int ms = 0; ms < 8; ms++) {
        f32x4 a0 = (f32x4)(0.0f), a1 = (f32x4)(0.0f);
#pragma unroll
        for (int ks = 0; ks < KS; ks++) {
            short8 a = __builtin_bit_cast(short8, sA[(ms * 16 + col) * LSTR + ks * 4 + quad]);
            a0 = __builtin_amdgcn_mfma_f32_16x16x32_bf16(a, b[0][ks], a0, 0, 0, 0);
            a1 = __builtin_amdgcn_mfma_f32_16x16x32_bf16(a, b[1][ks], a1, 0, 0, 0);
        }
        float* crow = Cslot + (size_t)(panel * 128 + ms * 16 + quad * 4) * G3 + g0;
#pragma unroll
        for (int r = 0; r < 4; r++) {
            crow[(size_t)r * G3]      = (a0[r] + bia0) * scl;
            crow[(size_t)r * G3 + 16] = (a1[r] + bia1) * scl;
        }
    }
}

// ---- pipelined mega-kernel ----
// Launch c: blocks [0,64)    scan0 chunk c-1  (64 WGs x 4 batches)
//           blocks [64,128)  scan1 chunk c-3
//           blocks [128,256) gemm units (x2 per block, 3 iters): gemm0(c), gemm1(c-2)
// All cross-stage deps satisfied by stream-ordered prior launches.
__global__ __launch_bounds__(512, 2) void pipe(
    int c,
    const unsigned short* xb,
    unsigned short* h1b,
    const i32x4* gbp0, const i32x4* gbp1,
    const float* bc0, const float* bc1,
    float* gx0, float* gx1,                   // 2-slot rings, [b][TC][G3] per slot
    const i32x4* whp0, const i32x4* whp1,
    const float* bhh0, const float* bhh1,
    float* hst0, float* hst1)                 // fp32 h-state [B][HID]
{
    __shared__ __attribute__((aligned(16))) char SM[16896 + 135168];

    const int bid = blockIdx.x;
    const int tid = threadIdx.x;

    if (bid < 128) {
        // ================= scan role (4 batches/WG) =================
        const bool L0 = bid < 64;
        const int cs = L0 ? c - 1 : c - 3;
        if (cs < 0 || cs >= NC) return;
        const float* gxslot = (L0 ? gx0 : gx1) + (size_t)(cs & 1) * SLOTP_F;
        const float* bhh = L0 ? bhh0 : bhh1;
        float* hstate = L0 ? hst0 : hst1;
        unsigned short* h1o = L0 ? h1b : nullptr;
        const int wg = L0 ? bid : bid - 64;

        unsigned short* hs = (unsigned short*)SM;   // [2][16*HSTRIDE]

        const int wave = tid >> 6, lane = tid & 63;
        const int col = lane & 15, quad = lane >> 4;
        const int jbase = wave * 32, j0 = jbase + col, j1 = jbase + 16 + col;
        const int bq  = wg * 4 + quad;        // this lane's batch
        const int row = quad * 4;             // its live MFMA row

        // packed weights: [e][tid] -> 48 fully-coalesced dwordx4 per thread
        const i32x4* wp = (L0 ? whp0 : whp1) + tid;
        i32x4 wrz[2][2][8];   // [gate][jt][ks] -> 128 pinned VGPRs
#pragma unroll
        for (int g = 0; g < 2; g++)
#pragma unroll
            for (int jt = 0; jt < 2; jt++)
#pragma unroll
                for (int ks = 0; ks < 8; ks++)
                    wrz[g][jt][ks] = wp[((g * 2 + jt) * 8 + ks) * 512];
        i32x4 wn0[8], wn1r[8];
#pragma unroll
        for (int ks = 0; ks < 8; ks++) {
            wn0[ks]  = wp[(32 + ks) * 512];
            wn1r[ks] = wp[(40 + ks) * 512];
        }

        // zero both h buffers (rows != 0 mod 4 stay zero: MFMA padding)
        for (int i = tid; i < 2 * 16 * HSTRIDE; i += 512) hs[i] = 0;

        float hreg[2];
        if (cs == 0) { hreg[0] = 0.0f; hreg[1] = 0.0f; }
        else {
            hreg[0] = hstate[bq * HID + j0];
            hreg[1] = hstate[bq * HID + j1];
        }
        float bhn[2] = { bhh[2 * HID + j0], bhh[2 * HID + j1] };

        __syncthreads();
        // seed live rows of buffer 0 with bf16(state) == monolithic LDS content
        hs[row * HSTRIDE + j0] = f2bf(hreg[0]);
        hs[row * HSTRIDE + j1] = f2bf(hreg[1]);
        __syncthreads();

        int gof = (bq * TC) * G3 + j0;
        int hof = (bq * SEQT + cs * TC) * HID + j0;
        const int abase = col * HSTRIDE + quad * 8;
        const int wbase = row * HSTRIDE + j0;

        // 2-deep gx prefetch (gc = lt, gc1 = lt+1, gc2 = lt+2 in flight).
        float gc[3][2], gc1[3][2], gc2[3][2];
#pragma unroll
        for (int g3 = 0; g3 < 3; g3++) {
            gc[g3][0] = gxslot[gof + g3 * HID];
            gc[g3][1] = gxslot[gof + g3 * HID + 16];
        }
        gof += G3;
#pragma unroll
        for (int g3 = 0; g3 < 3; g3++) {
            gc1[g3][0] = gxslot[gof + g3 * HID];
            gc1[g3][1] = gxslot[gof + g3 * HID + 16];
        }
        gof += G3;

        for (int lt = 0; lt < TC; lt++) {
            unsigned short* hc = hs + (lt & 1) * 16 * HSTRIDE;
            unsigned short* hn = hs + ((lt & 1) ^ 1) * 16 * HSTRIDE;

            // pin weight regs: opaque per-iter redefinition blocks remat/sinking
#pragma unroll
            for (int g = 0; g < 2; g++)
#pragma unroll
                for (int jt = 0; jt < 2; jt++)
#pragma unroll
                    for (int ks = 0; ks < 8; ks++)
                        asm volatile("" : "+v"(wrz[g][jt][ks]));
#pragma unroll
            for (int ks = 0; ks < 8; ks++) {
                asm volatile("" : "+v"(wn0[ks]));
                asm volatile("" : "+v"(wn1r[ks]));
            }

            // issue prefetch for lt+2 (slot tail-padded by 2 rows; tail discarded)
#pragma unroll
            for (int g3 = 0; g3 < 3; g3++) {
                gc2[g3][0] = gxslot[gof + g3 * HID];
                gc2[g3][1] = gxslot[gof + g3 * HID + 16];
            }
            gof += G3;

            f32x4 acc[3][2];
#pragma unroll
            for (int g = 0; g < 3; g++)
#pragma unroll
                for (int jt = 0; jt < 2; jt++) acc[g][jt] = (f32x4)(0.0f);

            __builtin_amdgcn_s_setprio(1);
#pragma unroll
            for (int ks = 0; ks < 8; ks++) {
                short8 a = *(const short8*)(&hc[abase + ks * 32]);
                acc[0][0] = __builtin_amdgcn_mfma_f32_16x16x32_bf16(a, __builtin_bit_cast(short8, wrz[0][0][ks]), acc[0][0], 0, 0, 0);
                acc[0][1] = __builtin_amdgcn_mfma_f32_16x16x32_bf16(a, __builtin_bit_cast(short8, wrz[0][1][ks]), acc[0][1], 0, 0, 0);
                acc[1][0] = __builtin_amdgcn_mfma_f32_16x16x32_bf16(a, __builtin_bit_cast(short8, wrz[1][0][ks]), acc[1][0], 0, 0, 0);
                acc[1][1] = __builtin_amdgcn_mfma_f32_16x16x32_bf16(a, __builtin_bit_cast(short8, wrz[1][1][ks]), acc[1][1], 0, 0, 0);
                acc[2][0] = __builtin_amdgcn_mfma_f32_16x16x32_bf16(a, __builtin_bit_cast(short8, wn0[ks]),       acc[2][0], 0, 0, 0);
                acc[2][1] = __builtin_amdgcn_mfma_f32_16x16x32_bf16(a, __builtin_bit_cast(short8, wn1r[ks]),      acc[2][1], 0, 0, 0);
            }
            __builtin_amdgcn_s_setprio(0);

            unsigned short hb[2];
#pragma unroll
            for (int jt = 0; jt < 2; jt++) {
                float er = exp2fast(__builtin_fmaf(acc[0][jt][0], NLOG2E, gc[0][jt]));
                float rr = __builtin_amdgcn_rcpf(1.0f + er);
                float ez = exp2fast(__builtin_fmaf(acc[1][jt][0], NLOG2E, gc[1][jt]));
                float zz = __builtin_amdgcn_rcpf(1.0f + ez);
                float inner = acc[2][jt][0] + bhn[jt];
                float en = exp2fast(__builtin_fmaf(rr * inner, LOG2E2, gc[2][jt]));
                float nn = __builtin_fmaf(__builtin_amdgcn_rcpf(1.0f + en), -2.0f, 1.0f);
                float hnew = __builtin_fmaf(zz, hreg[jt] - nn, nn);
                hreg[jt] = hnew;
                hb[jt] = f2bf(hnew);
                hn[wbase + jt * 16] = hb[jt];
            }

            if (h1o) {
                h1o[hof]      = hb[0];
                h1o[hof + 16] = hb[1];
            }
            hof += HID;

            // rotate prefetch buffers (static-indexed register moves)
#pragma unroll
            for (int g3 = 0; g3 < 3; g3++) {
                gc[g3][0]  = gc1[g3][0];  gc[g3][1]  = gc1[g3][1];
                gc1[g3][0] = gc2[g3][0];  gc1[g3][1] = gc2[g3][1];
            }

            scan_barrier();   // lgkm drain + s_barrier; global ops stay in flight
        }

        // persist fp32 state for next chunk (hst1 after last chunk == fc input)
        hstate[bq * HID + j0] = hreg[0];
        hstate[bq * HID + j1] = hreg[1];

    } else {
        // ================= gemm role =================
        const int cg0 = c, cg1 = c - 2;
        const int G0t = (cg0 < NC) ? G0TILES : 0;
        const int G1t = (cg1 >= 0 && cg1 < NC) ? G0TILES : 0;
        if (G0t + G1t == 0) return;

        i32x4* sA = (i32x4*)(SM + 16896) + (tid >> 8) * 4224;
        const int u    = (bid - 128) * 2 + (tid >> 8);   // unit id [0,256)
        const int tidu = tid & 255;
        float* c0slot = gx0 + (size_t)(cg0 & 1) * SLOTP_F;
        float* c1slot = gx1 + (size_t)(cg1 & 1) * SLOTP_F;

        short8 bf[2][8];
        float bia0, bia1; int g0c;

#pragma unroll 1
        for (int it = 0; it < 3; it++) {
            int t = it * 256 + u;
            int mode = (t < G0t) ? 0 : ((t - G0t < G1t) ? 1 : -1);
            int tile = (mode == 1) ? t - G0t : t;
            if (mode == 0)
                g_stage<IND>(sA, tile, cg0 * TC, xb, gbp0, bc0, tidu, bf, bia0, bia1, g0c);
            else if (mode == 1)
                g_stage<HID>(sA, tile, cg1 * TC, h1b, gbp1, bc1, tidu, bf, bia0, bia1, g0c);
            __syncthreads();
            if (mode == 0)
                g_comp<IND>(sA, tile, bf, bia0, bia1, g0c, c0slot, tidu);
            else if (mode == 1)
                g_comp<HID>(sA, tile, bf, bia0, bia1, g0c, c1slot, tidu);
            __syncthreads();
        }
    }
}

// out[256,118] = hlast[256,256] @ fcW[118,256]^T + fcb
__global__ __launch_bounds__(128) void fc_kernel(
    const float* __restrict__ hlast, const float* __restrict__ W,
    const float* __restrict__ b, float* __restrict__ out)
{
    __shared__ float hsm[HID];
    int bidx = blockIdx.x;
    for (int i = threadIdx.x; i < HID; i += 128) hsm[i] = hlast[(size_t)bidx * HID + i];
    __syncthreads();
    int o = threadIdx.x;
    if (o < OUTD) {
        float acc = b[o];
        const float* wrow = W + (size_t)o * HID;
#pragma unroll 4
        for (int k = 0; k < HID; k++) acc += hsm[k] * wrow[k];
        out[(size_t)bidx * OUTD + o] = acc;
    }
}

extern "C" void kernel_launch(void* const* d_in, const int* in_sizes, int n_in,
                              void* d_out, int out_size, void* d_ws, size_t ws_size,
                              hipStream_t stream) {
    const float* x    = (const float*)d_in[0];
    const float* Wih0 = (const float*)d_in[1];
    const float* Whh0 = (const float*)d_in[2];
    const float* bih0 = (const float*)d_in[3];
    const float* bhh0 = (const float*)d_in[4];
    const float* Wih1 = (const float*)d_in[5];
    const float* Whh1 = (const float*)d_in[6];
    const float* bih1 = (const float*)d_in[7];
    const float* bhh1 = (const float*)d_in[8];
    const float* fcW  = (const float*)d_in[9];
    const float* fcb  = (const float*)d_in[10];
    float* out = (float*)d_out;

    char* ws = (char*)d_ws;
    size_t off = 0;
    auto walloc = [&](size_t bytes) {
        void* p = ws + off;
        off = (off + bytes + 255) & ~(size_t)255;
        return p;
    };

    const int M = BATCH * SEQT;                       // 51200
    unsigned short* xb   = (unsigned short*)walloc((size_t)XSZ * 2);         // 13.1 MB
    float*          gx0  = (float*)         walloc((size_t)2 * SLOTP_F * 4); // 39.3 MB
    float*          gx1  = (float*)         walloc((size_t)2 * SLOTP_F * 4); // 39.3 MB
    unsigned short* h1b  = (unsigned short*)walloc((size_t)M * HID * 2);     // 26.2 MB
    unsigned short* w0b  = (unsigned short*)walloc((size_t)W0SZ * 2);
    unsigned short* wh0b = (unsigned short*)walloc((size_t)WHSZ * 2);
    unsigned short* w1b  = (unsigned short*)walloc((size_t)WHSZ * 2);
    unsigned short* wh1b = (unsigned short*)walloc((size_t)WHSZ * 2);
    i32x4*          whp0 = (i32x4*)         walloc((size_t)SCANPK_L * 16);   // 393 KB
    i32x4*          whp1 = (i32x4*)         walloc((size_t)SCANPK_L * 16);
    i32x4*          gbp0 = (i32x4*)         walloc((size_t)G0PK * 16);       // 196 KB
    i32x4*          gbp1 = (i32x4*)         walloc((size_t)G1PK * 16);       // 393 KB
    float*          bc0  = (float*)         walloc(G3 * 4);
    float*          bc1  = (float*)         walloc(G3 * 4);
    float*          hst0 = (float*)         walloc((size_t)BATCH * HID * 4);
    float*          hst1 = (float*)         walloc((size_t)BATCH * HID * 4);

    cvt_all     <<<2048, 256, 0, stream>>>(x, Wih0, Whh0, Wih1, Whh1,
                                           xb, w0b, wh0b, w1b, wh1b);
    pack_weights<<<(PKTOT + 255) / 256, 256, 0, stream>>>(
                                           wh0b, wh1b, w0b, w1b,
                                           whp0, whp1, gbp0, gbp1);
    combine_bias<<<6,    256, 0, stream>>>(bih0, bhh0, bih1, bhh1, bc0, bc1);

    // pipeline: launch c = { gemm0(c) | scan0(c-1) | gemm1(c-2) | scan1(c-3) }
    for (int c = 0; c <= NC + 2; ++c)
        pipe<<<256, 512, 0, stream>>>(c, xb, h1b, gbp0, gbp1, bc0, bc1,
                                      gx0, gx1, whp0, whp1, bhh0, bhh1, hst0, hst1);

    fc_kernel<<<BATCH, 128, 0, stream>>>(hst1, fcW, fcb, out);
}